// Round 2
// baseline (65.752 us; speedup 1.0000x reference)
//
#include <hip/hip_runtime.h>

#define TILE_W 64
#define TILE_H 32
#define HALO 5
#define RAW_H 42          // TILE_H + 2*HALO
#define RAW_W 74          // TILE_W + 2*HALO
#define RAW_S 76          // padded stride
#define US 72             // m3/M3 width (windows starting at col 0..71)
#define WS 64
#define IMG 512
#define NBATCH 32

__device__ __forceinline__ float nan0(float v) { return v == v ? v : 0.0f; }

__global__ __launch_bounds__(256)
void simplenet_fused(const float* __restrict__ X,
                     const float* __restrict__ w0, const float* __restrict__ b0,
                     const float* __restrict__ w1, const float* __restrict__ w2,
                     const float* __restrict__ w3, const float* __restrict__ w4,
                     const float* __restrict__ w5, const float* __restrict__ w6,
                     float* __restrict__ out)
{
    __shared__ float RAW[RAW_H][RAW_S];   // raw tile + halo; later aliased for h11-max
    __shared__ float U[RAW_H][US];        // 3-wide running min
    __shared__ float V[RAW_H][US];        // 3-wide running max
    __shared__ float Wb[RAW_H][WS];       // gaussH, then h11-min

    const int tid = threadIdx.x;
    const int xo  = tid & 63;             // column within tile
    const int ty  = tid >> 6;             // 0..3
    const int y0  = ty * 8;               // 8 consecutive output rows per thread
    const int tx0 = blockIdx.x * TILE_W;
    const int ty0 = blockIdx.y * TILE_H;
    const int b   = blockIdx.z;

    const float* Xb = X + (size_t)b * (IMG * IMG);

    // load 1x1 weights early (uniform -> s_load, latency hidden under staging)
    const float W0c0 = w0[0], W0c1 = w0[1];
    const float B0   = b0[0], B1   = b0[1];
    const float W1c0 = w1[0], W1c1 = w1[1];
    const float W2c0 = w2[0], W2c1 = w2[1];
    const float W3c0 = w3[0], W3c1 = w3[1];
    const float W4c0 = w4[0], W4c1 = w4[1];
    const float W5c0 = w5[0], W5c1 = w5[1];
    const float W6c0 = w6[0], W6c1 = w6[1];

    // ---- P0: stage tile + halo. OOB = NaN sentinel:
    //  pools: v_min/v_max ignore NaN (== +-inf padding); convs: nan0() per tap (== 0 padding)
    for (int idx = tid; idx < RAW_H * RAW_W; idx += 256) {
        const int r = idx / RAW_W;
        const int c = idx - r * RAW_W;
        const int gy = ty0 - HALO + r;
        const int gx = tx0 - HALO + c;
        float v = __builtin_nanf("");
        if ((unsigned)gy < IMG && (unsigned)gx < IMG)
            v = Xb[gy * IMG + gx];
        RAW[r][c] = v;
    }
    __syncthreads();

    float a0[8], a1[8];

    // ---- P1a: identity + 3x3 cross blur (center always interior)
#pragma unroll
    for (int p = 0; p < 8; ++p) {
        const int yr = y0 + p + HALO, xc = xo + HALO;
        const float x  = RAW[yr][xc];
        const float cr = 0.25f * (nan0(RAW[yr-1][xc]) + nan0(RAW[yr+1][xc])
                                + nan0(RAW[yr][xc-1]) + nan0(RAW[yr][xc+1]));
        a0[p] = B0 + W0c0 * x + W1c0 * cr;
        a1[p] = B1 + W0c1 * x + W1c1 * cr;
    }

    // ---- P1b: gauss horizontal pass (rows 2..39 suffice for v-window)
    const float G[7] = {0.10628875f, 0.14032194f, 0.16577342f, 0.17523179f,
                        0.16577342f, 0.14032194f, 0.10628875f};
    for (int idx = tid; idx < 38 * 64; idx += 256) {
        const int r = 2 + (idx >> 6);
        const int c = idx & 63;
        float s = 0.f;
#pragma unroll
        for (int k = 0; k < 7; ++k) s += G[k] * nan0(RAW[r][c + 2 + k]);
        Wb[r][c] = s;
    }
    __syncthreads();

    // ---- P2a: gauss vertical (8 consecutive rows share the 14-tap column)
    {
        float w[14];
#pragma unroll
        for (int i = 0; i < 14; ++i) w[i] = Wb[y0 + 2 + i][xo];
#pragma unroll
        for (int p = 0; p < 8; ++p) {
            float s = 0.f;
#pragma unroll
            for (int j = 0; j < 7; ++j) s += G[j] * w[p + j];
            a0[p] += W2c0 * s;
            a1[p] += W2c1 * s;
        }
    }

    // ---- P2b: 3-wide running min/max (shared by pool3-h and pool11-h)
    for (int idx = tid; idx < RAW_H * US; idx += 256) {
        const int r = idx / US;
        const int c = idx - r * US;
        const float v0 = RAW[r][c], v1 = RAW[r][c+1], v2 = RAW[r][c+2];
        U[r][c] = fminf(fminf(v0, v1), v2);
        V[r][c] = fmaxf(fmaxf(v0, v1), v2);
    }
    __syncthreads();

    // ---- P3a: pool3 vertical straight from U/V (h3 at col xo == U[.][xo+4])
    {
        float u[10], v[10];
#pragma unroll
        for (int i = 0; i < 10; ++i) { u[i] = U[y0+4+i][xo+4]; v[i] = V[y0+4+i][xo+4]; }
#pragma unroll
        for (int p = 0; p < 8; ++p) {
            const float mn = fminf(fminf(u[p], u[p+1]), u[p+2]);
            const float mx = fmaxf(fmaxf(v[p], v[p+1]), v[p+2]);
            a0[p] += W3c0 * mn + W5c0 * mx;
            a1[p] += W3c1 * mn + W5c1 * mx;
        }
    }

    // ---- P3b: h11 via m3-composition: window [c..c+10] = U[c],U[c+3],U[c+6],U[c+8]
    // min -> Wb (gaussH dead), max -> RAW alias (RAW dead after P2b)
    for (int idx = tid; idx < RAW_H * WS; idx += 256) {
        const int r = idx >> 6;
        const int c = idx & 63;
        Wb[r][c]  = fminf(fminf(U[r][c], U[r][c+3]), fminf(U[r][c+6], U[r][c+8]));
        RAW[r][c] = fmaxf(fmaxf(V[r][c], V[r][c+3]), fmaxf(V[r][c+6], V[r][c+8]));
    }
    __syncthreads();

    // ---- P4: pool11 vertical, van Herk over 18 rows (window 11, 8 outputs)
    {
        float hn[18], hx[18];
#pragma unroll
        for (int i = 0; i < 18; ++i) { hn[i] = Wb[y0 + i][xo]; hx[i] = RAW[y0 + i][xo]; }

        float sufn[11], sufx[11];
        sufn[10] = hn[10]; sufx[10] = hx[10];
#pragma unroll
        for (int i = 9; i >= 0; --i) {
            sufn[i] = fminf(hn[i], sufn[i+1]);
            sufx[i] = fmaxf(hx[i], sufx[i+1]);
        }
        float pren = hn[11], prex = hx[11];
        a0[0] += W4c0 * sufn[0] + W6c0 * sufx[0];
        a1[0] += W4c1 * sufn[0] + W6c1 * sufx[0];
#pragma unroll
        for (int p = 1; p < 8; ++p) {
            const float mn = fminf(sufn[p], pren);
            const float mx = fmaxf(sufx[p], prex);
            a0[p] += W4c0 * mn + W6c0 * mx;
            a1[p] += W4c1 * mn + W6c1 * mx;
            if (p < 7) { pren = fminf(pren, hn[p+11]); prex = fmaxf(prex, hx[p+11]); }
        }
    }

    // ---- stores: both channel planes, coalesced per row
    float* out0 = out + ((size_t)b * 2 + 0) * (IMG * IMG);
    float* out1 = out + ((size_t)b * 2 + 1) * (IMG * IMG);
#pragma unroll
    for (int p = 0; p < 8; ++p) {
        const int gy = ty0 + y0 + p;
        const int gx = tx0 + xo;
        out0[gy * IMG + gx] = a0[p];
        out1[gy * IMG + gx] = a1[p];
    }
}

extern "C" void kernel_launch(void* const* d_in, const int* in_sizes, int n_in,
                              void* d_out, int out_size, void* d_ws, size_t ws_size,
                              hipStream_t stream) {
    const float* X  = (const float*)d_in[0];
    const float* w0 = (const float*)d_in[1];
    const float* b0 = (const float*)d_in[2];
    const float* w1 = (const float*)d_in[3];
    const float* w2 = (const float*)d_in[4];
    const float* w3 = (const float*)d_in[5];
    const float* w4 = (const float*)d_in[6];
    const float* w5 = (const float*)d_in[7];
    const float* w6 = (const float*)d_in[8];
    float* out = (float*)d_out;

    dim3 grid(IMG / TILE_W, IMG / TILE_H, NBATCH);
    simplenet_fused<<<grid, 256, 0, stream>>>(X, w0, b0, w1, w2, w3, w4, w5, w6, out);
}

// Round 3
// 50.558 us; speedup vs baseline: 1.3005x; 1.3005x over previous
//
#include <hip/hip_runtime.h>

#define IMG 512
#define TW 64
#define TH 16
#define RROWS 26      // TH + 2*5
#define RST 80        // RAW stride: col j <-> gx = tx0 - 8 + j (16B-aligned float4 staging)
#define UST 72        // U/V width: q <-> RAW cols q+3..q+5

__device__ __forceinline__ float nan0(float v) { return v == v ? v : 0.0f; }
__device__ __forceinline__ float min3f(float a, float b, float c){ return fminf(fminf(a,b),c); }
__device__ __forceinline__ float max3f(float a, float b, float c){ return fmaxf(fmaxf(a,b),c); }

__global__ __launch_bounds__(256)
void simplenet_fused(const float* __restrict__ X,
                     const float* __restrict__ w0, const float* __restrict__ b0,
                     const float* __restrict__ w1, const float* __restrict__ w2,
                     const float* __restrict__ w3, const float* __restrict__ w4,
                     const float* __restrict__ w5, const float* __restrict__ w6,
                     float* __restrict__ out)
{
    __shared__ float RAW[RROWS][RST];   // 8320 B : raw tile (NaN = OOB sentinel)
    __shared__ float UB[RROWS][UST];    // 7488 B : 3-wide running min, then running max
    __shared__ float B2[RROWS][TW];     // 6656 B : gaussH, then h11min, then h11max

    const int tid = threadIdx.x;
    const int xo  = tid & 63;           // output column within tile
    const int ty  = tid >> 6;           // 0..3
    const int y0  = ty * 4;             // 4 consecutive output rows per thread
    const int bx = blockIdx.x, by = blockIdx.y, bz = blockIdx.z;
    const int tx0 = bx * TW, ty0 = by * TH;
    const bool xe = (bx == 0) || (bx == IMG/TW - 1);   // block touches x image edge
    const bool ye = (by == 0) || (by == IMG/TH - 1);   // block touches y image edge
    const float* Xb = X + (size_t)bz * (IMG*IMG);

    // 1x1 weights (uniform -> scalar loads)
    const float W0c0 = w0[0], W0c1 = w0[1];
    const float B0   = b0[0], B1   = b0[1];
    const float W1c0 = w1[0], W1c1 = w1[1];
    const float W2c0 = w2[0], W2c1 = w2[1];
    const float W3c0 = w3[0], W3c1 = w3[1];
    const float W4c0 = w4[0], W4c1 = w4[1];
    const float W5c0 = w5[0], W5c1 = w5[1];
    const float W6c0 = w6[0], W6c1 = w6[1];

    // ---- stage RAW (NaN sentinel for OOB) ----
    if (!xe) {
        // interior-x: float4 path, columns always valid
        for (int t = tid; t < RROWS*20; t += 256) {
            const int r = t / 20, c4 = t - r*20;
            const int gy = ty0 - 5 + r;
            float4 v;
            if (!ye || (unsigned)gy < IMG)
                v = *(const float4*)(Xb + gy*IMG + (tx0 - 8 + 4*c4));
            else {
                const float qn = __builtin_nanf("");
                v = make_float4(qn, qn, qn, qn);
            }
            *(float4*)(&RAW[r][4*c4]) = v;
        }
    } else {
        for (int t = tid; t < RROWS*RST; t += 256) {
            const int r = t / RST, c = t - r*RST;
            const int gy = ty0 - 5 + r, gx = tx0 - 8 + c;
            RAW[r][c] = ((unsigned)gy < IMG && (unsigned)gx < IMG)
                        ? Xb[gy*IMG + gx] : __builtin_nanf("");
        }
    }
    __syncthreads();

    float a0[4], a1[4];

    // ---- P1: identity + 3x3 cross blur ----
    {
        const int xc = xo + 8;
        float c0 = RAW[y0+4][xc], c1 = RAW[y0+5][xc], c2 = RAW[y0+6][xc],
              c3 = RAW[y0+7][xc], c4 = RAW[y0+8][xc], c5 = RAW[y0+9][xc];
        float l0 = RAW[y0+5][xc-1], l1 = RAW[y0+6][xc-1], l2 = RAW[y0+7][xc-1], l3 = RAW[y0+8][xc-1];
        float r0 = RAW[y0+5][xc+1], r1 = RAW[y0+6][xc+1], r2 = RAW[y0+7][xc+1], r3 = RAW[y0+8][xc+1];
        if (ye) { c0 = nan0(c0); c5 = nan0(c5); }       // only outermost vertical taps can be OOB
        if (xe) { l0=nan0(l0); l1=nan0(l1); l2=nan0(l2); l3=nan0(l3);
                  r0=nan0(r0); r1=nan0(r1); r2=nan0(r2); r3=nan0(r3); }
        const float cc[6] = {c0,c1,c2,c3,c4,c5};
        const float ll[4] = {l0,l1,l2,l3};
        const float rr[4] = {r0,r1,r2,r3};
#pragma unroll
        for (int p = 0; p < 4; ++p) {
            const float cr = 0.25f * (cc[p] + cc[p+2] + ll[p] + rr[p]);
            a0[p] = B0 + W0c0*cc[p+1] + W1c0*cr;
            a1[p] = B1 + W0c1*cc[p+1] + W1c1*cr;
        }
    }

    // ---- P2: gauss horizontal (symmetric 7-tap) -> B2 rows 0..21 ----
    const float G0 = 0.10628875f, G1 = 0.14032194f, G2 = 0.16577342f, G3 = 0.17523179f;
    for (int gi = ty; gi < 22; gi += 4) {
        const int rr2 = gi + 2;
        float x0 = RAW[rr2][xo+5],  x1 = RAW[rr2][xo+6], x2 = RAW[rr2][xo+7],
              x3 = RAW[rr2][xo+8],  x4 = RAW[rr2][xo+9], x5 = RAW[rr2][xo+10],
              x6 = RAW[rr2][xo+11];
        if (xe) { x0=nan0(x0); x1=nan0(x1); x2=nan0(x2);
                  x4=nan0(x4); x5=nan0(x5); x6=nan0(x6); }   // center col x3 always valid
        B2[gi][xo] = G0*(x0+x6) + G1*(x1+x5) + G2*(x2+x4) + G3*x3;
        // NaN rows (y-edge) stay NaN here; cleaned in P3
    }
    __syncthreads();

    // ---- P3: gauss vertical (accumulate) ----
    {
        float wv[10];
#pragma unroll
        for (int i = 0; i < 10; ++i) wv[i] = B2[y0+i][xo];
        if (ye) {
#pragma unroll
            for (int i = 0; i < 10; ++i) wv[i] = nan0(wv[i]);
        }
#pragma unroll
        for (int p = 0; p < 4; ++p) {
            const float s = G0*(wv[p]+wv[p+6]) + G1*(wv[p+1]+wv[p+5])
                          + G2*(wv[p+2]+wv[p+4]) + G3*wv[p+3];
            a0[p] += W2c0*s; a1[p] += W2c1*s;
        }
    }
    // ---- P4a: U = 3-col running min (shared by pool3 and h11-min) ----
    for (int r = ty; r < RROWS; r += 4)
        UB[r][xo] = min3f(RAW[r][xo+3], RAW[r][xo+4], RAW[r][xo+5]);
    {
        const int r = tid >> 3;
        if (r < RROWS) {
            const int q = 64 + (tid & 7);
            UB[r][q] = min3f(RAW[r][q+3], RAW[r][q+4], RAW[r][q+5]);
        }
    }
    __syncthreads();

    // ---- P5a: pool3-min (U[.][xo+4] is the 3-wide h-min at this column) ----
    {
        float u0 = UB[y0+4][xo+4], u1 = UB[y0+5][xo+4], u2 = UB[y0+6][xo+4],
              u3 = UB[y0+7][xo+4], u4 = UB[y0+8][xo+4], u5 = UB[y0+9][xo+4];
        const float m0 = min3f(u0,u1,u2), m1 = min3f(u1,u2,u3),
                    m2 = min3f(u2,u3,u4), m3 = min3f(u3,u4,u5);
        a0[0] += W3c0*m0; a1[0] += W3c1*m0;
        a0[1] += W3c0*m1; a1[1] += W3c1*m1;
        a0[2] += W3c0*m2; a1[2] += W3c1*m2;
        a0[3] += W3c0*m3; a1[3] += W3c1*m3;
    }
    // ---- P6a: h11-min via composition of U taps -> B2 ----
    for (int r = ty; r < RROWS; r += 4)
        B2[r][xo] = fminf(fminf(UB[r][xo], UB[r][xo+3]), fminf(UB[r][xo+6], UB[r][xo+8]));
    __syncthreads();

    // ---- P7a: v11-min (van Herk, window 11, 4 outputs) + P4b: V = 3-col running max ----
    {
        float h[14];
#pragma unroll
        for (int i = 0; i < 14; ++i) h[i] = B2[y0+i][xo];
        float acc = h[10];
#pragma unroll
        for (int i = 9; i >= 4; --i) acc = fminf(acc, h[i]);
        const float S3 = fminf(acc, h[3]);
        const float S2 = fminf(S3, h[2]);
        const float S1 = fminf(S2, h[1]);
        const float S0 = fminf(S1, h[0]);
        const float p1 = h[11], p2 = fminf(p1, h[12]), p3 = fminf(p2, h[13]);
        const float o0 = S0, o1 = fminf(S1,p1), o2 = fminf(S2,p2), o3 = fminf(S3,p3);
        a0[0] += W4c0*o0; a1[0] += W4c1*o0;
        a0[1] += W4c0*o1; a1[1] += W4c1*o1;
        a0[2] += W4c0*o2; a1[2] += W4c1*o2;
        a0[3] += W4c0*o3; a1[3] += W4c1*o3;
    }
    for (int r = ty; r < RROWS; r += 4)
        UB[r][xo] = max3f(RAW[r][xo+3], RAW[r][xo+4], RAW[r][xo+5]);
    {
        const int r = tid >> 3;
        if (r < RROWS) {
            const int q = 64 + (tid & 7);
            UB[r][q] = max3f(RAW[r][q+3], RAW[r][q+4], RAW[r][q+5]);
        }
    }
    __syncthreads();

    // ---- P5b: pool3-max + P6b: h11-max -> B2 ----
    {
        float u0 = UB[y0+4][xo+4], u1 = UB[y0+5][xo+4], u2 = UB[y0+6][xo+4],
              u3 = UB[y0+7][xo+4], u4 = UB[y0+8][xo+4], u5 = UB[y0+9][xo+4];
        const float m0 = max3f(u0,u1,u2), m1 = max3f(u1,u2,u3),
                    m2 = max3f(u2,u3,u4), m3 = max3f(u3,u4,u5);
        a0[0] += W5c0*m0; a1[0] += W5c1*m0;
        a0[1] += W5c0*m1; a1[1] += W5c1*m1;
        a0[2] += W5c0*m2; a1[2] += W5c1*m2;
        a0[3] += W5c0*m3; a1[3] += W5c1*m3;
    }
    for (int r = ty; r < RROWS; r += 4)
        B2[r][xo] = fmaxf(fmaxf(UB[r][xo], UB[r][xo+3]), fmaxf(UB[r][xo+6], UB[r][xo+8]));
    __syncthreads();

    // ---- P7b: v11-max + store ----
    {
        float h[14];
#pragma unroll
        for (int i = 0; i < 14; ++i) h[i] = B2[y0+i][xo];
        float acc = h[10];
#pragma unroll
        for (int i = 9; i >= 4; --i) acc = fmaxf(acc, h[i]);
        const float S3 = fmaxf(acc, h[3]);
        const float S2 = fmaxf(S3, h[2]);
        const float S1 = fmaxf(S2, h[1]);
        const float S0 = fmaxf(S1, h[0]);
        const float p1 = h[11], p2 = fmaxf(p1, h[12]), p3 = fmaxf(p2, h[13]);
        const float o0 = S0, o1 = fmaxf(S1,p1), o2 = fmaxf(S2,p2), o3 = fmaxf(S3,p3);
        a0[0] += W6c0*o0; a1[0] += W6c1*o0;
        a0[1] += W6c0*o1; a1[1] += W6c1*o1;
        a0[2] += W6c0*o2; a1[2] += W6c1*o2;
        a0[3] += W6c0*o3; a1[3] += W6c1*o3;
    }

    float* o0p = out + ((size_t)bz*2 + 0)*(IMG*IMG) + (size_t)(ty0+y0)*IMG + tx0 + xo;
    float* o1p = o0p + (IMG*IMG);
#pragma unroll
    for (int p = 0; p < 4; ++p) {
        o0p[(size_t)p*IMG] = a0[p];
        o1p[(size_t)p*IMG] = a1[p];
    }
}

extern "C" void kernel_launch(void* const* d_in, const int* in_sizes, int n_in,
                              void* d_out, int out_size, void* d_ws, size_t ws_size,
                              hipStream_t stream) {
    const float* X  = (const float*)d_in[0];
    const float* w0 = (const float*)d_in[1];
    const float* b0 = (const float*)d_in[2];
    const float* w1 = (const float*)d_in[3];
    const float* w2 = (const float*)d_in[4];
    const float* w3 = (const float*)d_in[5];
    const float* w4 = (const float*)d_in[6];
    const float* w5 = (const float*)d_in[7];
    const float* w6 = (const float*)d_in[8];
    float* out = (float*)d_out;

    dim3 grid(IMG / TW, IMG / TH, 32);
    simplenet_fused<<<grid, 256, 0, stream>>>(X, w0, b0, w1, w2, w3, w4, w5, w6, out);
}